// Round 1
// baseline (5964.808 us; speedup 1.0000x reference)
//
#include <hip/hip_runtime.h>
#include <math.h>

#define B_ 8
#define D_ 256
#define T_ 8192
#define NQ 8
#define KB 1024
#define TT 64           // timesteps per workgroup
#define NTHR 256
#define KC 256          // k-chunk
#define DCH 32          // d staging chunk
#define RP 260          // residual LDS pitch (floats, 16B-aligned, breaks bank stride)
#define CP 260          // cbs LDS pitch (floats)

#define OUT_CODES (B_ * D_ * T_)              // 16777216
#define OUT_BW (OUT_CODES + NQ * B_ * T_)     // 17301504
#define OUT_LOSS (OUT_BW + 1)

#define R_BYTES (TT * RP * 4)                 // 66560
#define U_BYTES (DCH * CP * 4)                // 33280 (cbs; reused for argmin reduce)
#define LDS_TOTAL (R_BYTES + U_BYTES + 16)    // + wsum[4]

// ---------------- init: row norms of codebooks + scalar outputs ----------------
__global__ void init_cbsq_kernel(const float* __restrict__ cb, const int* __restrict__ sr,
                                 float* __restrict__ csq, float* __restrict__ out) {
    int gid = blockIdx.x * blockDim.x + threadIdx.x;
    int row = gid >> 6;          // 8192 rows, one wave each
    int lane = gid & 63;
    float4 v = ((const float4*)(cb + (size_t)row * D_))[lane];
    float s = fmaf(v.x, v.x, fmaf(v.y, v.y, fmaf(v.z, v.z, v.w * v.w)));
#pragma unroll
    for (int off = 32; off; off >>= 1) s += __shfl_down(s, off);
    if (lane == 0) csq[row] = s;
    if (gid == 0) {
        // bw = n_q * log2(bins) * sr / 1000 = 80 * sr / 1000
        out[OUT_BW] = (float)(*sr) * (80.0f / 1000.0f);
        out[OUT_LOSS] = 0.0f;
    }
}

// ---------------- main RVQ kernel ----------------
extern "C" __global__ __launch_bounds__(NTHR, 1)
void rvq_kernel(const float* __restrict__ x, const float* __restrict__ cb,
                const float* __restrict__ csq, float* __restrict__ out) {
    extern __shared__ char smem[];
    float* rsm = (float*)smem;                         // [TT][RP]
    float* cbs = (float*)(smem + R_BYTES);             // [DCH][CP], k-interleaved
    float* redv = cbs;                                 // [64][33] (reuse after compute)
    int* redi = (int*)(smem + R_BYTES + 8448);         // [64][33]
    int* sel = (int*)(smem + R_BYTES + 16896);         // [64]
    float* wsum = (float*)(smem + R_BYTES + U_BYTES);  // [4]

    const int tid = threadIdx.x;
    const int b = blockIdx.x >> 7;            // grid = 8 * 128
    const int t0 = (blockIdx.x & 127) * TT;
    const int ttg = tid >> 5;                 // 8 groups of 8 timesteps
    const int kg = tid & 31;                  // 32 k-groups of 8 codes
    const float* xb = x + (size_t)b * D_ * T_;

    // load residual tile: rsm[tt][d] = x[b][d][t0+tt]  (coalesced over t)
    {
        const int tl = tid & 63;
        for (int d = tid >> 6; d < D_; d += 4)
            rsm[tl * RP + d] = xb[(size_t)d * T_ + t0 + tl];
    }

    float ssq = 0.0f;

    for (int q = 0; q < NQ; ++q) {
        const float* cbq = cb + (size_t)q * KB * D_;
        const float* csqq = csq + q * KB;
        float bval[8];
        int bidx[8];
#pragma unroll
        for (int i = 0; i < 8; ++i) { bval[i] = INFINITY; bidx[i] = 0; }

        for (int kc = 0; kc < KB / KC; ++kc) {
            float acc[8][8];
#pragma unroll
            for (int i = 0; i < 8; ++i)
#pragma unroll
                for (int j = 0; j < 8; ++j) acc[i][j] = 0.0f;

            for (int dc = 0; dc < D_; dc += DCH) {
                __syncthreads();  // cbs free to overwrite (also orders residual update / sel reads)
                // stage cb[kc*KC + kk][dc + d] -> cbs[d][pcol(kk)], pcol = j1*128 + kg*4 + j0
                {
                    const int kk0 = tid >> 3;
                    const int d4 = (tid & 7) << 2;
#pragma unroll
                    for (int p = 0; p < 8; ++p) {
                        const int kk = kk0 + (p << 5);
                        const float4 v = *(const float4*)(cbq + (size_t)(kc * KC + kk) * D_ + dc + d4);
                        const int pcol = ((kk >> 2) & 1) * 128 + (kk >> 3) * 4 + (kk & 3);
                        cbs[(d4 + 0) * CP + pcol] = v.x;
                        cbs[(d4 + 1) * CP + pcol] = v.y;
                        cbs[(d4 + 2) * CP + pcol] = v.z;
                        cbs[(d4 + 3) * CP + pcol] = v.w;
                    }
                }
                __syncthreads();
                for (int dd = 0; dd < DCH; dd += 4) {
                    float4 rf[8];
#pragma unroll
                    for (int i = 0; i < 8; ++i)
                        rf[i] = *(const float4*)&rsm[(ttg * 8 + i) * RP + dc + dd];
                    float4 cf0[4], cf1[4];
#pragma unroll
                    for (int dl = 0; dl < 4; ++dl) {
                        cf0[dl] = *(const float4*)&cbs[(dd + dl) * CP + kg * 4];
                        cf1[dl] = *(const float4*)&cbs[(dd + dl) * CP + 128 + kg * 4];
                    }
#pragma unroll
                    for (int i = 0; i < 8; ++i) {
#pragma unroll
                        for (int dl = 0; dl < 4; ++dl) {
                            const float rr = ((const float*)&rf[i])[dl];
                            acc[i][0] = fmaf(rr, cf0[dl].x, acc[i][0]);
                            acc[i][1] = fmaf(rr, cf0[dl].y, acc[i][1]);
                            acc[i][2] = fmaf(rr, cf0[dl].z, acc[i][2]);
                            acc[i][3] = fmaf(rr, cf0[dl].w, acc[i][3]);
                            acc[i][4] = fmaf(rr, cf1[dl].x, acc[i][4]);
                            acc[i][5] = fmaf(rr, cf1[dl].y, acc[i][5]);
                            acc[i][6] = fmaf(rr, cf1[dl].z, acc[i][6]);
                            acc[i][7] = fmaf(rr, cf1[dl].w, acc[i][7]);
                        }
                    }
                }
            }
            // distance + running best (k ascending within thread -> strict < keeps first)
            const float4 c0 = *(const float4*)(csqq + kc * KC + kg * 8);
            const float4 c1 = *(const float4*)(csqq + kc * KC + kg * 8 + 4);
            const float cs[8] = {c0.x, c0.y, c0.z, c0.w, c1.x, c1.y, c1.z, c1.w};
#pragma unroll
            for (int i = 0; i < 8; ++i) {
#pragma unroll
                for (int j = 0; j < 8; ++j) {
                    const float dist = fmaf(-2.0f, acc[i][j], cs[j]);
                    if (dist < bval[i]) { bval[i] = dist; bidx[i] = kc * KC + kg * 8 + j; }
                }
            }
        }
        __syncthreads();  // compute done; cbs area reusable as reduce scratch
#pragma unroll
        for (int i = 0; i < 8; ++i) {
            redv[(ttg * 8 + i) * 33 + kg] = bval[i];
            redi[(ttg * 8 + i) * 33 + kg] = bidx[i];
        }
        __syncthreads();
        if (tid < TT) {
            float bv = redv[tid * 33];
            int bi = redi[tid * 33];
#pragma unroll
            for (int g = 1; g < 32; ++g) {
                float v = redv[tid * 33 + g];
                int ii = redi[tid * 33 + g];
                if (v < bv || (v == bv && ii < bi)) { bv = v; bi = ii; }  // jnp.argmin: first min
            }
            sel[tid] = bi;
            out[OUT_CODES + ((size_t)q * B_ + b) * T_ + t0 + tid] = (float)bi;
        }
        __syncthreads();
        // residual update: r[tt][:] -= cb[sel[tt]][:]; accumulate ssq of new residual
        {
            const int tt = tid >> 2;
            const int dp = (tid & 3) << 6;
            const float* crow = cbq + (size_t)sel[tt] * D_ + dp;
            float* rrow = rsm + tt * RP + dp;
#pragma unroll
            for (int dd = 0; dd < 64; dd += 4) {
                const float4 c = *(const float4*)(crow + dd);
                float4 rv = *(float4*)(rrow + dd);
                rv.x -= c.x; rv.y -= c.y; rv.z -= c.z; rv.w -= c.w;
                *(float4*)(rrow + dd) = rv;
                ssq = fmaf(rv.x, rv.x, ssq);
                ssq = fmaf(rv.y, rv.y, ssq);
                ssq = fmaf(rv.z, rv.z, ssq);
                ssq = fmaf(rv.w, rv.w, ssq);
            }
        }
        // next q's first __syncthreads orders these writes before compute reads
    }
    __syncthreads();
    // quantized = x - r_final, layout [B][D][T]
    {
        const int tl = tid & 63;
        float* outq = out + (size_t)b * D_ * T_;
        for (int d = tid >> 6; d < D_; d += 4) {
            const size_t gi = (size_t)d * T_ + t0 + tl;
            outq[gi] = xb[gi] - rsm[tl * RP + d];
        }
    }
    // commit loss partial: wave reduce -> block reduce -> one atomic
#pragma unroll
    for (int off = 32; off; off >>= 1) ssq += __shfl_down(ssq, off);
    if ((tid & 63) == 0) wsum[tid >> 6] = ssq;
    __syncthreads();
    if (tid == 0) {
        const float scale = 0.25f / ((float)NQ * (float)B_ * (float)D_ * (float)T_);
        atomicAdd(out + OUT_LOSS, (wsum[0] + wsum[1] + wsum[2] + wsum[3]) * scale);
    }
}

extern "C" void kernel_launch(void* const* d_in, const int* in_sizes, int n_in,
                              void* d_out, int out_size, void* d_ws, size_t ws_size,
                              hipStream_t stream) {
    const float* x = (const float*)d_in[0];
    const int* sr = (const int*)d_in[1];
    const float* cb = (const float*)d_in[2];
    float* out = (float*)d_out;
    float* csq = (float*)d_ws;  // 8192 floats = 32 KB scratch

    // ~100 KB dynamic LDS (gfx950 allows 160 KB/workgroup); set attr defensively every call
    hipFuncSetAttribute((const void*)rvq_kernel, hipFuncAttributeMaxDynamicSharedMemorySize,
                        LDS_TOTAL);

    init_cbsq_kernel<<<2048, 256, 0, stream>>>(cb, sr, csq, out);
    rvq_kernel<<<B_ * (T_ / TT), NTHR, LDS_TOTAL, stream>>>(x, cb, csq, out);
}

// Round 4
// 3085.975 us; speedup vs baseline: 1.9329x; 1.9329x over previous
//
#include <hip/hip_runtime.h>
#include <math.h>

typedef _Float16 f16;
typedef f16 f16x8 __attribute__((ext_vector_type(8)));
typedef float f32x4 __attribute__((ext_vector_type(4)));

#define B_ 8
#define D_ 256
#define T_ 8192
#define NQ 8
#define KB 1024
#define TT 64
#define NTHR 256
#define RSP 520                       // residual pitch in halves (pad breaks banks)
#define SCALE_UP 2048.0f
#define SCALE_DN 4.8828125e-4f        // 2^-11

#define OUT_CODES (B_ * D_ * T_)      // 16777216
#define OUT_BW (OUT_CODES + NQ * B_ * T_)
#define OUT_LOSS (OUT_BW + 1)

#define R_BYTES (TT * RSP * 2)        // 66560
#define BTILE 32768                   // 512 codes x 32 halves x 2B
#define BBUF_OFF R_BYTES
#define RED_OFF (BBUF_OFF + 2 * BTILE)   // 132096
#define REDI_OFF (RED_OFF + 1024)
#define SEL_OFF (REDI_OFF + 1024)
#define WSUM_OFF (SEL_OFF + 256)
#define LDS_TOTAL (WSUM_OFF + 16)     // 134416 < 160K

// workspace layout
#define WS_HI (8192 * 4)              // csq first (32KB)
#define CBW_HALVES (NQ * 8 * KB * 32) // 2,097,152 halves per array
#define WS_LO (WS_HI + CBW_HALVES * 2)

// Explicit drain of all outstanding global_load_lds writes. The compiler
// normally emits s_waitcnt vmcnt(0) before s_barrier (m97 dump), but that is
// not guaranteed from source; if elided, the double-buffer pipeline races on
// warm-cache (graph replay) timing. Free when the counter is already 0.
#define DRAIN_VMEM() asm volatile("s_waitcnt vmcnt(0)" ::: "memory")

// ---------------- init: codebook row norms (fp32) + scalar outputs ----------------
__global__ void init_cbsq_kernel(const float* __restrict__ cb, const int* __restrict__ sr,
                                 float* __restrict__ csq, float* __restrict__ out) {
    int gid = blockIdx.x * blockDim.x + threadIdx.x;
    int row = gid >> 6;
    int lane = gid & 63;
    float4 v = ((const float4*)(cb + (size_t)row * D_))[lane];
    float s = fmaf(v.x, v.x, fmaf(v.y, v.y, fmaf(v.z, v.z, v.w * v.w)));
#pragma unroll
    for (int off = 32; off; off >>= 1) s += __shfl_down(s, off);
    if (lane == 0) csq[row] = s;
    if (gid == 0) {
        out[OUT_BW] = (float)(*sr) * (80.0f / 1000.0f);
        out[OUT_LOSS] = 0.0f;
    }
}

// ---------------- init: split codebook into f16 hi + scaled-lo, [q][dc8][code][32] ----------------
__global__ void init_split_kernel(const float* __restrict__ cb, f16* __restrict__ whi,
                                  f16* __restrict__ wlo) {
    int gid = blockIdx.x * 256 + threadIdx.x;   // (q*8+dc)*1024 + k
    int qdc = gid >> 10, k = gid & 1023;
    int q = qdc >> 3, dc = qdc & 7;
    const float* src = cb + ((size_t)(q * 1024 + k)) * 256 + dc * 32;
    size_t wo = (size_t)gid * 32;
#pragma unroll
    for (int jj = 0; jj < 4; ++jj) {
        float4 a = ((const float4*)src)[jj * 2];
        float4 c = ((const float4*)src)[jj * 2 + 1];
        float vals[8] = {a.x, a.y, a.z, a.w, c.x, c.y, c.z, c.w};
        f16x8 hv, lv;
#pragma unroll
        for (int i = 0; i < 8; ++i) {
            f16 h = (f16)vals[i];
            hv[i] = h;
            lv[i] = (f16)((vals[i] - (float)h) * SCALE_UP);   // scaled lo: no f16 underflow
        }
        *(f16x8*)&whi[wo + jj * 8] = hv;
        *(f16x8*)&wlo[wo + jj * 8] = lv;
    }
}

// ---------------- async stage one 32KB B-tile (XOR-swizzled at 16B granularity) ----------------
__device__ __forceinline__ void stage_tile(const f16* __restrict__ whi, const f16* __restrict__ wlo,
                                           char* smem, int g, int tid) {
    const int q = g >> 5, r5 = g & 31;
    const int s = (r5 >> 4) & 1, kind = (r5 >> 3) & 1, dc = r5 & 7;
    const f16* gt = (kind ? wlo : whi) + ((size_t)((q * 8 + dc) * 1024 + s * 512)) * 32;
    char* lb = smem + BBUF_OFF + (g & 1) * BTILE;
#pragma unroll
    for (int j = 0; j < 8; ++j) {
        const int v = j * 256 + tid;
        const int u = v ^ ((v >> 3) & 7);          // fetch-side swizzle (self-inverse in low bits)
        const f16* gp = gt + (size_t)u * 8;
        char* lp = lb + (j * 4096 + (tid & 192) * 16);   // wave-uniform base; lane writes +lane*16
        __builtin_amdgcn_global_load_lds((const __attribute__((address_space(1))) void*)gp,
                                         (__attribute__((address_space(3))) void*)lp, 16, 0, 0);
    }
}

// ---------------- main RVQ kernel: 4-product split-f16 MFMA GEMM + fused argmin ----------------
extern "C" __global__ __launch_bounds__(NTHR, 1)
void rvq_kernel(const float* __restrict__ x, const float* __restrict__ cb,
                const float* __restrict__ csq, const f16* __restrict__ whi,
                const f16* __restrict__ wlo, float* __restrict__ out) {
    extern __shared__ char smem[];
    f16* rs = (f16*)smem;                          // [64][520]: cols 0..255 h1, 256..511 h2s

    const int tid = threadIdx.x;
    const int w = tid >> 6;
    const int l = tid & 63;
    const int l15 = l & 15;
    const int q4 = l >> 4;
    const int ww = l15 * 4 + q4;
    const int swzo = (ww ^ ((ww >> 3) & 7)) * 8;   // B-frag swizzled offset, halves

    const int b = blockIdx.x >> 7;
    const int t0 = (blockIdx.x & 127) * TT;
    const float* xb = x + (size_t)b * D_ * T_;

    stage_tile(whi, wlo, smem, 0, tid);            // prefetch first tile, overlaps rs init

    // residual init: rs[t][d] split of x[b][d][t0+t] (coalesced over t)
    for (int d = tid >> 6; d < D_; d += 4) {
        float v = xb[(size_t)d * T_ + t0 + l];
        f16 h = (f16)v;
        rs[l * RSP + d] = h;
        rs[l * RSP + 256 + d] = (f16)((v - (float)h) * SCALE_UP);
    }

    float ssq = 0.0f;
    const f16 kdn = (f16)SCALE_DN;

    for (int q = 0; q < NQ; ++q) {
        const float* cbq = cb + (size_t)q * KB * D_;
        float bval[16];
        int bidx[16];
#pragma unroll
        for (int e = 0; e < 16; ++e) { bval[e] = INFINITY; bidx[e] = 0; }

        for (int s = 0; s < 2; ++s) {
            f32x4 ah[4][8], am[4][8];
#pragma unroll
            for (int mt = 0; mt < 4; ++mt)
#pragma unroll
                for (int nt = 0; nt < 8; ++nt) { ah[mt][nt] = (f32x4)0.0f; am[mt][nt] = (f32x4)0.0f; }

#pragma unroll 1
            for (int st2 = 0; st2 < 16; ++st2) {
                const int g = q * 32 + s * 16 + st2;
                DRAIN_VMEM();                       // stage(g) writes visible before barrier
                __syncthreads();                    // all waves' reads of buf[(g+1)&1] done
                if (g + 1 < NQ * 32) stage_tile(whi, wlo, smem, g + 1, tid);
                const int dc = st2 & 7;
                const f16* bb = (const f16*)(smem + BBUF_OFF + (g & 1) * BTILE);
                f16x8 bf[8];
#pragma unroll
                for (int nt = 0; nt < 8; ++nt)
                    bf[nt] = *(const f16x8*)&bb[w * 4096 + nt * 512 + swzo];
                const int cb0 = dc * 32 + q4 * 8;
                if (st2 < 8) {
                    // B = b1 tile: h1*b1 -> ah ; h2s*b1 -> am (scale 2^11)
#pragma unroll
                    for (int mt = 0; mt < 4; ++mt) {
                        f16x8 af = *(const f16x8*)&rs[(mt * 16 + l15) * RSP + cb0];
#pragma unroll
                        for (int nt = 0; nt < 8; ++nt)
                            ah[mt][nt] = __builtin_amdgcn_mfma_f32_16x16x32_f16(af, bf[nt], ah[mt][nt], 0, 0, 0);
                    }
#pragma unroll
                    for (int mt = 0; mt < 4; ++mt) {
                        f16x8 af = *(const f16x8*)&rs[(mt * 16 + l15) * RSP + 256 + cb0];
#pragma unroll
                        for (int nt = 0; nt < 8; ++nt)
                            am[mt][nt] = __builtin_amdgcn_mfma_f32_16x16x32_f16(af, bf[nt], am[mt][nt], 0, 0, 0);
                    }
                } else {
                    // B = b2s tile: h1*b2s -> am (scale 2^11) ; (h2s*2^-11)*b2s -> am (scale 2^11)
#pragma unroll
                    for (int mt = 0; mt < 4; ++mt) {
                        f16x8 af = *(const f16x8*)&rs[(mt * 16 + l15) * RSP + cb0];
#pragma unroll
                        for (int nt = 0; nt < 8; ++nt)
                            am[mt][nt] = __builtin_amdgcn_mfma_f32_16x16x32_f16(af, bf[nt], am[mt][nt], 0, 0, 0);
                    }
#pragma unroll
                    for (int mt = 0; mt < 4; ++mt) {
                        f16x8 af = *(const f16x8*)&rs[(mt * 16 + l15) * RSP + 256 + cb0];
                        f16x8 afu = af * kdn;      // true lo (ll term; rare subnormal loss ~2e-7)
#pragma unroll
                        for (int nt = 0; nt < 8; ++nt)
                            am[mt][nt] = __builtin_amdgcn_mfma_f32_16x16x32_f16(afu, bf[nt], am[mt][nt], 0, 0, 0);
                    }
                }
            }
            // fold sweep into per-lane running best (codes ascending -> strict < keeps first)
            const int cbase = s * 512 + w * 128 + l15;
#pragma unroll
            for (int nt = 0; nt < 8; ++nt) {
                const int code = cbase + nt * 16;
                const float cq = csq[q * KB + code];
#pragma unroll
                for (int mt = 0; mt < 4; ++mt)
#pragma unroll
                    for (int rg = 0; rg < 4; ++rg) {
                        const float dot = fmaf(am[mt][nt][rg], SCALE_DN, ah[mt][nt][rg]);
                        const float dist = fmaf(-2.0f, dot, cq);
                        const int e = mt * 4 + rg;
                        if (dist < bval[e]) { bval[e] = dist; bidx[e] = code; }
                    }
            }
        }
        // butterfly across the 16 lanes sharing each t (xor masks < 16 stay in group)
#pragma unroll
        for (int m = 1; m < 16; m <<= 1) {
#pragma unroll
            for (int e = 0; e < 16; ++e) {
                const float ov = __shfl_xor(bval[e], m);
                const int oi = __shfl_xor(bidx[e], m);
                if (ov < bval[e] || (ov == bval[e] && oi < bidx[e])) { bval[e] = ov; bidx[e] = oi; }
            }
        }
        float* redv = (float*)(smem + RED_OFF);
        int* redi = (int*)(smem + REDI_OFF);
        int* sel = (int*)(smem + SEL_OFF);
        if (l15 == 0) {
#pragma unroll
            for (int mt = 0; mt < 4; ++mt)
#pragma unroll
                for (int rg = 0; rg < 4; ++rg) {
                    const int t = mt * 16 + q4 * 4 + rg;   // C-layout row ownership
                    redv[w * 64 + t] = bval[mt * 4 + rg];
                    redi[w * 64 + t] = bidx[mt * 4 + rg];
                }
        }
        DRAIN_VMEM();
        __syncthreads();
        if (tid < TT) {
            float bv = redv[tid];
            int bi = redi[tid];
#pragma unroll
            for (int w2 = 1; w2 < 4; ++w2) {
                const float v = redv[w2 * 64 + tid];
                const int ii = redi[w2 * 64 + tid];
                if (v < bv || (v == bv && ii < bi)) { bv = v; bi = ii; }
            }
            sel[tid] = bi;
            out[OUT_CODES + ((size_t)q * B_ + b) * T_ + t0 + tid] = (float)bi;
        }
        DRAIN_VMEM();
        __syncthreads();
        // residual update: reconstruct fp32 = h1 + h2s*2^-11, subtract cb row, re-split; ssq
        {
            const int t = tid >> 2, dp = tid & 3;
            const float* crow = cbq + (size_t)sel[t] * D_ + dp * 64;
            f16* rrh = rs + t * RSP + dp * 64;
            f16* rrl = rs + t * RSP + 256 + dp * 64;
#pragma unroll
            for (int i0 = 0; i0 < 64; i0 += 8) {
                f16x8 hv = *(const f16x8*)&rrh[i0];
                f16x8 lv = *(const f16x8*)&rrl[i0];
                const float4 c0 = *(const float4*)&crow[i0];
                const float4 c1 = *(const float4*)&crow[i0 + 4];
                const float cc[8] = {c0.x, c0.y, c0.z, c0.w, c1.x, c1.y, c1.z, c1.w};
                f16x8 nh, nl;
#pragma unroll
                for (int i = 0; i < 8; ++i) {
                    const float r = fmaf((float)lv[i], SCALE_DN, (float)hv[i]);
                    const float nv = r - cc[i];
                    ssq = fmaf(nv, nv, ssq);
                    const f16 h = (f16)nv;
                    nh[i] = h;
                    nl[i] = (f16)((nv - (float)h) * SCALE_UP);
                }
                *(f16x8*)&rrh[i0] = nh;
                *(f16x8*)&rrl[i0] = nl;
            }
        }
        // next sweep's first __syncthreads orders rs writes before A-frag reads
    }
    __syncthreads();
    // quantized = x - r_final, [B][D][T], coalesced over t
    {
        float* outq = out + (size_t)b * D_ * T_;
        for (int d = tid >> 6; d < D_; d += 4) {
            const float r = fmaf((float)rs[l * RSP + 256 + d], SCALE_DN, (float)rs[l * RSP + d]);
            const size_t gi = (size_t)d * T_ + t0 + l;
            outq[gi] = xb[gi] - r;
        }
    }
    // commit loss: wave reduce -> block reduce -> one atomic
#pragma unroll
    for (int off = 32; off; off >>= 1) ssq += __shfl_down(ssq, off);
    float* wsum = (float*)(smem + WSUM_OFF);
    if (l == 0) wsum[w] = ssq;
    __syncthreads();
    if (tid == 0) {
        const float scale = 0.25f / ((float)NQ * (float)B_ * (float)D_ * (float)T_);
        atomicAdd(out + OUT_LOSS, (wsum[0] + wsum[1] + wsum[2] + wsum[3]) * scale);
    }
}

extern "C" void kernel_launch(void* const* d_in, const int* in_sizes, int n_in,
                              void* d_out, int out_size, void* d_ws, size_t ws_size,
                              hipStream_t stream) {
    const float* x = (const float*)d_in[0];
    const int* sr = (const int*)d_in[1];
    const float* cb = (const float*)d_in[2];
    float* out = (float*)d_out;
    float* csq = (float*)d_ws;
    f16* whi = (f16*)((char*)d_ws + WS_HI);
    f16* wlo = (f16*)((char*)d_ws + WS_LO);

    hipFuncSetAttribute((const void*)rvq_kernel, hipFuncAttributeMaxDynamicSharedMemorySize,
                        LDS_TOTAL);

    init_cbsq_kernel<<<2048, 256, 0, stream>>>(cb, sr, csq, out);
    init_split_kernel<<<256, 256, 0, stream>>>(cb, whi, wlo);
    rvq_kernel<<<B_ * (T_ / TT), NTHR, LDS_TOTAL, stream>>>(x, cb, csq, whi, wlo, out);
}

// Round 5
// 1819.255 us; speedup vs baseline: 3.2787x; 1.6963x over previous
//
#include <hip/hip_runtime.h>
#include <math.h>

typedef _Float16 f16;
typedef f16 f16x8 __attribute__((ext_vector_type(8)));
typedef float f32x4 __attribute__((ext_vector_type(4)));

#define B_ 8
#define D_ 256
#define T_ 8192
#define NQ 8
#define KB 1024
#define TT 64
#define NTHR 256
#define RSP 520                       // residual pitch in halves (pad breaks banks)
#define SCALE_UP 2048.0f
#define SCALE_DN 4.8828125e-4f        // 2^-11

#define OUT_CODES (B_ * D_ * T_)      // 16777216
#define OUT_BW (OUT_CODES + NQ * B_ * T_)
#define OUT_LOSS (OUT_BW + 1)

#define R_BYTES (TT * RSP * 2)        // 66560
#define BTILE 16384                   // 256 codes x 32 halves x 2B
#define BBUF_OFF R_BYTES
#define RED_OFF (BBUF_OFF + 2 * BTILE)   // 99328
#define REDI_OFF (RED_OFF + 1024)
#define SEL_OFF (REDI_OFF + 1024)
#define WSUM_OFF (SEL_OFF + 256)
#define LDS_TOTAL (WSUM_OFF + 16)     // 101648 < 160K (1 block/CU)

// workspace layout
#define WS_HI (8192 * 4)              // csq first (32KB)
#define CBW_HALVES (NQ * 8 * KB * 32) // 2,097,152 halves per array
#define WS_LO (WS_HI + CBW_HALVES * 2)

// Explicit drain of outstanding global_load_lds before barriers (R4: required
// for graph-replay correctness; free when counter already 0).
#define DRAIN_VMEM() asm volatile("s_waitcnt vmcnt(0)" ::: "memory")

// ---------------- init: codebook row norms (fp32) + scalar outputs ----------------
__global__ void init_cbsq_kernel(const float* __restrict__ cb, const int* __restrict__ sr,
                                 float* __restrict__ csq, float* __restrict__ out) {
    int gid = blockIdx.x * blockDim.x + threadIdx.x;
    int row = gid >> 6;
    int lane = gid & 63;
    float4 v = ((const float4*)(cb + (size_t)row * D_))[lane];
    float s = fmaf(v.x, v.x, fmaf(v.y, v.y, fmaf(v.z, v.z, v.w * v.w)));
#pragma unroll
    for (int off = 32; off; off >>= 1) s += __shfl_down(s, off);
    if (lane == 0) csq[row] = s;
    if (gid == 0) {
        out[OUT_BW] = (float)(*sr) * (80.0f / 1000.0f);
        out[OUT_LOSS] = 0.0f;
    }
}

// ---------------- init: split codebook into f16 hi + scaled-lo, [q][dc8][code][32] ----------------
__global__ void init_split_kernel(const float* __restrict__ cb, f16* __restrict__ whi,
                                  f16* __restrict__ wlo) {
    int gid = blockIdx.x * 256 + threadIdx.x;   // (q*8+dc)*1024 + k
    int qdc = gid >> 10, k = gid & 1023;
    int q = qdc >> 3, dc = qdc & 7;
    const float* src = cb + ((size_t)(q * 1024 + k)) * 256 + dc * 32;
    size_t wo = (size_t)gid * 32;
#pragma unroll
    for (int jj = 0; jj < 4; ++jj) {
        float4 a = ((const float4*)src)[jj * 2];
        float4 c = ((const float4*)src)[jj * 2 + 1];
        float vals[8] = {a.x, a.y, a.z, a.w, c.x, c.y, c.z, c.w};
        f16x8 hv, lv;
#pragma unroll
        for (int i = 0; i < 8; ++i) {
            f16 h = (f16)vals[i];
            hv[i] = h;
            lv[i] = (f16)((vals[i] - (float)h) * SCALE_UP);   // scaled lo: no f16 underflow
        }
        *(f16x8*)&whi[wo + jj * 8] = hv;
        *(f16x8*)&wlo[wo + jj * 8] = lv;
    }
}

// ---------------- async stage one 16KB B-tile (XOR-swizzled at 16B granularity) ----------------
// g = q*64 + s*16 + kind*8 + dc : codes [s*256,s*256+256) x dims [dc*32,dc*32+32)
__device__ __forceinline__ void stage_tile(const f16* __restrict__ whi, const f16* __restrict__ wlo,
                                           char* smem, int g, int tid) {
    const int q = g >> 6, r6 = g & 63;
    const int s = r6 >> 4, kind = (r6 >> 3) & 1, dc = r6 & 7;
    const f16* gt = (kind ? wlo : whi) + ((size_t)((q * 8 + dc) * 1024 + s * 256)) * 32;
    char* lb = smem + BBUF_OFF + (g & 1) * BTILE;
#pragma unroll
    for (int j = 0; j < 4; ++j) {
        const int v = j * 256 + tid;               // 16B-unit index in tile [0,1024)
        const int u = v ^ ((v >> 3) & 7);          // fetch-side swizzle (self-inverse in low bits)
        const f16* gp = gt + (size_t)u * 8;
        char* lp = lb + (j * 4096 + (tid & 192) * 16);   // wave-uniform base; lane writes +lane*16
        __builtin_amdgcn_global_load_lds((const __attribute__((address_space(1))) void*)gp,
                                         (__attribute__((address_space(3))) void*)lp, 16, 0, 0);
    }
}

// ---------------- main RVQ kernel: 4-product split-f16 MFMA GEMM + fused argmin ----------------
extern "C" __global__ __launch_bounds__(NTHR, 1)
void rvq_kernel(const float* __restrict__ x, const float* __restrict__ cb,
                const float* __restrict__ csq, const f16* __restrict__ whi,
                const f16* __restrict__ wlo, float* __restrict__ out) {
    extern __shared__ char smem[];
    f16* rs = (f16*)smem;                          // [64][520]: cols 0..255 h1, 256..511 h2s

    const int tid = threadIdx.x;
    const int w = tid >> 6;
    const int l = tid & 63;
    const int l15 = l & 15;
    const int q4 = l >> 4;
    const int ww = l15 * 4 + q4;
    const int swzo = (ww ^ ((ww >> 3) & 7)) * 8;   // B-frag swizzled offset, halves

    const int b = blockIdx.x >> 7;
    const int t0 = (blockIdx.x & 127) * TT;
    const float* xb = x + (size_t)b * D_ * T_;

    stage_tile(whi, wlo, smem, 0, tid);            // prefetch first tile, overlaps rs init

    // residual init: rs[t][d] split of x[b][d][t0+t] (coalesced over t)
    for (int d = tid >> 6; d < D_; d += 4) {
        float v = xb[(size_t)d * T_ + t0 + l];
        f16 h = (f16)v;
        rs[l * RSP + d] = h;
        rs[l * RSP + 256 + d] = (f16)((v - (float)h) * SCALE_UP);
    }

    float ssq = 0.0f;
    const f16 kdn = (f16)SCALE_DN;

    for (int q = 0; q < NQ; ++q) {
        const float* cbq = cb + (size_t)q * KB * D_;
        float bval[16];
        int bidx[16];
#pragma unroll
        for (int e = 0; e < 16; ++e) { bval[e] = INFINITY; bidx[e] = 0; }

        for (int s = 0; s < 4; ++s) {              // 4 sweeps of 256 codes
            f32x4 ah[4][4], am[4][4];              // 128 acc VGPRs: fits, no spill
#pragma unroll
            for (int mt = 0; mt < 4; ++mt)
#pragma unroll
                for (int nt = 0; nt < 4; ++nt) { ah[mt][nt] = (f32x4)0.0f; am[mt][nt] = (f32x4)0.0f; }

#pragma unroll 1
            for (int st2 = 0; st2 < 16; ++st2) {
                const int g = q * 64 + s * 16 + st2;
                DRAIN_VMEM();                       // stage(g) writes landed
                __syncthreads();                    // all reads of buf[(g+1)&1] done
                if (g + 1 < NQ * 64) stage_tile(whi, wlo, smem, g + 1, tid);
                const int dc = st2 & 7;
                const f16* bb = (const f16*)(smem + BBUF_OFF + (g & 1) * BTILE);
                f16x8 bf[4];
#pragma unroll
                for (int nt = 0; nt < 4; ++nt)
                    bf[nt] = *(const f16x8*)&bb[w * 2048 + nt * 512 + swzo];
                const int cb0 = dc * 32 + q4 * 8;
                if (st2 < 8) {
                    // B = b1 tile: h1*b1 -> ah ; h2s*b1 -> am (scale 2^11)
#pragma unroll
                    for (int mt = 0; mt < 4; ++mt) {
                        f16x8 af = *(const f16x8*)&rs[(mt * 16 + l15) * RSP + cb0];
#pragma unroll
                        for (int nt = 0; nt < 4; ++nt)
                            ah[mt][nt] = __builtin_amdgcn_mfma_f32_16x16x32_f16(af, bf[nt], ah[mt][nt], 0, 0, 0);
                    }
#pragma unroll
                    for (int mt = 0; mt < 4; ++mt) {
                        f16x8 af = *(const f16x8*)&rs[(mt * 16 + l15) * RSP + 256 + cb0];
#pragma unroll
                        for (int nt = 0; nt < 4; ++nt)
                            am[mt][nt] = __builtin_amdgcn_mfma_f32_16x16x32_f16(af, bf[nt], am[mt][nt], 0, 0, 0);
                    }
                } else {
                    // B = b2s tile: h1*b2s -> am ; (h2s*2^-11)*b2s -> am (ll term)
#pragma unroll
                    for (int mt = 0; mt < 4; ++mt) {
                        f16x8 af = *(const f16x8*)&rs[(mt * 16 + l15) * RSP + cb0];
#pragma unroll
                        for (int nt = 0; nt < 4; ++nt)
                            am[mt][nt] = __builtin_amdgcn_mfma_f32_16x16x32_f16(af, bf[nt], am[mt][nt], 0, 0, 0);
                    }
#pragma unroll
                    for (int mt = 0; mt < 4; ++mt) {
                        f16x8 af = *(const f16x8*)&rs[(mt * 16 + l15) * RSP + 256 + cb0];
                        f16x8 afu = af * kdn;      // true lo (rare subnormal loss ~2e-7)
#pragma unroll
                        for (int nt = 0; nt < 4; ++nt)
                            am[mt][nt] = __builtin_amdgcn_mfma_f32_16x16x32_f16(afu, bf[nt], am[mt][nt], 0, 0, 0);
                    }
                }
            }
            // fold sweep into per-lane running best (codes ascending -> strict < keeps first)
            const int cbase = s * 256 + w * 64 + l15;
#pragma unroll
            for (int nt = 0; nt < 4; ++nt) {
                const int code = cbase + nt * 16;
                const float cq = csq[q * KB + code];
#pragma unroll
                for (int mt = 0; mt < 4; ++mt)
#pragma unroll
                    for (int rg = 0; rg < 4; ++rg) {
                        const float dot = fmaf(am[mt][nt][rg], SCALE_DN, ah[mt][nt][rg]);
                        const float dist = fmaf(-2.0f, dot, cq);
                        const int e = mt * 4 + rg;
                        if (dist < bval[e]) { bval[e] = dist; bidx[e] = code; }
                    }
            }
        }
        // butterfly across the 16 lanes sharing each t (xor masks < 16 stay in group)
#pragma unroll
        for (int m = 1; m < 16; m <<= 1) {
#pragma unroll
            for (int e = 0; e < 16; ++e) {
                const float ov = __shfl_xor(bval[e], m);
                const int oi = __shfl_xor(bidx[e], m);
                if (ov < bval[e] || (ov == bval[e] && oi < bidx[e])) { bval[e] = ov; bidx[e] = oi; }
            }
        }
        float* redv = (float*)(smem + RED_OFF);
        int* redi = (int*)(smem + REDI_OFF);
        int* sel = (int*)(smem + SEL_OFF);
        if (l15 == 0) {
#pragma unroll
            for (int mt = 0; mt < 4; ++mt)
#pragma unroll
                for (int rg = 0; rg < 4; ++rg) {
                    const int t = mt * 16 + q4 * 4 + rg;   // C-layout row ownership
                    redv[w * 64 + t] = bval[mt * 4 + rg];
                    redi[w * 64 + t] = bidx[mt * 4 + rg];
                }
        }
        DRAIN_VMEM();
        __syncthreads();
        if (tid < TT) {
            float bv = redv[tid];
            int bi = redi[tid];
#pragma unroll
            for (int w2 = 1; w2 < 4; ++w2) {
                const float v = redv[w2 * 64 + tid];
                const int ii = redi[w2 * 64 + tid];
                if (v < bv || (v == bv && ii < bi)) { bv = v; bi = ii; }
            }
            sel[tid] = bi;
            out[OUT_CODES + ((size_t)q * B_ + b) * T_ + t0 + tid] = (float)bi;
        }
        DRAIN_VMEM();
        __syncthreads();
        // residual update: reconstruct fp32 = h1 + h2s*2^-11, subtract cb row, re-split; ssq
        {
            const int t = tid >> 2, dp = tid & 3;
            const float* crow = cbq + (size_t)sel[t] * D_ + dp * 64;
            f16* rrh = rs + t * RSP + dp * 64;
            f16* rrl = rs + t * RSP + 256 + dp * 64;
#pragma unroll
            for (int i0 = 0; i0 < 64; i0 += 8) {
                f16x8 hv = *(const f16x8*)&rrh[i0];
                f16x8 lv = *(const f16x8*)&rrl[i0];
                const float4 c0 = *(const float4*)&crow[i0];
                const float4 c1 = *(const float4*)&crow[i0 + 4];
                const float cc[8] = {c0.x, c0.y, c0.z, c0.w, c1.x, c1.y, c1.z, c1.w};
                f16x8 nh, nl;
#pragma unroll
                for (int i = 0; i < 8; ++i) {
                    const float r = fmaf((float)lv[i], SCALE_DN, (float)hv[i]);
                    const float nv = r - cc[i];
                    ssq = fmaf(nv, nv, ssq);
                    const f16 h = (f16)nv;
                    nh[i] = h;
                    nl[i] = (f16)((nv - (float)h) * SCALE_UP);
                }
                *(f16x8*)&rrh[i0] = nh;
                *(f16x8*)&rrl[i0] = nl;
            }
        }
        // next sweep's first __syncthreads orders rs writes before A-frag reads
    }
    __syncthreads();
    // quantized = x - r_final, [B][D][T], coalesced over t
    {
        float* outq = out + (size_t)b * D_ * T_;
        for (int d = tid >> 6; d < D_; d += 4) {
            const float r = fmaf((float)rs[l * RSP + 256 + d], SCALE_DN, (float)rs[l * RSP + d]);
            const size_t gi = (size_t)d * T_ + t0 + l;
            outq[gi] = xb[gi] - r;
        }
    }
    // commit loss: wave reduce -> block reduce -> one atomic
#pragma unroll
    for (int off = 32; off; off >>= 1) ssq += __shfl_down(ssq, off);
    float* wsum = (float*)(smem + WSUM_OFF);
    if (l == 0) wsum[w] = ssq;
    __syncthreads();
    if (tid == 0) {
        const float scale = 0.25f / ((float)NQ * (float)B_ * (float)D_ * (float)T_);
        atomicAdd(out + OUT_LOSS, (wsum[0] + wsum[1] + wsum[2] + wsum[3]) * scale);
    }
}

extern "C" void kernel_launch(void* const* d_in, const int* in_sizes, int n_in,
                              void* d_out, int out_size, void* d_ws, size_t ws_size,
                              hipStream_t stream) {
    const float* x = (const float*)d_in[0];
    const int* sr = (const int*)d_in[1];
    const float* cb = (const float*)d_in[2];
    float* out = (float*)d_out;
    float* csq = (float*)d_ws;
    f16* whi = (f16*)((char*)d_ws + WS_HI);
    f16* wlo = (f16*)((char*)d_ws + WS_LO);

    hipFuncSetAttribute((const void*)rvq_kernel, hipFuncAttributeMaxDynamicSharedMemorySize,
                        LDS_TOTAL);

    init_cbsq_kernel<<<2048, 256, 0, stream>>>(cb, sr, csq, out);
    init_split_kernel<<<256, 256, 0, stream>>>(cb, whi, wlo);
    rvq_kernel<<<B_ * (T_ / TT), NTHR, LDS_TOTAL, stream>>>(x, cb, csq, whi, wlo, out);
}

// Round 6
// 1510.605 us; speedup vs baseline: 3.9486x; 1.2043x over previous
//
#include <hip/hip_runtime.h>
#include <math.h>

typedef _Float16 f16;
typedef f16 f16x8 __attribute__((ext_vector_type(8)));
typedef float f32x4 __attribute__((ext_vector_type(4)));

#define B_ 8
#define D_ 256
#define T_ 8192
#define NQ 8
#define KB 1024
#define TT 64
#define NTHR 256
#define SCALE_UP 2048.0f
#define SCALE_DN 4.8828125e-4f        // 2^-11

#define OUT_CODES (B_ * D_ * T_)      // 16777216
#define OUT_BW (OUT_CODES + NQ * B_ * T_)
#define OUT_LOSS (OUT_BW + 1)

// rs: 64 rows x 512 halves (h1 at cols 0..255, h2s at 256..511), XOR-swizzled:
// logical (t, granule g of 8 halves) stored at granule g ^ (t & 7). No pad.
#define R_BYTES 65536
#define BTILE 32768                   // super-tile: 256 codes x 32 halves x 2B x 2 kinds
#define BBUF_OFF R_BYTES              // 65536; double-buffered 64 KB
#define RED_OFF (BBUF_OFF + 2 * BTILE)   // 131072
#define REDI_OFF (RED_OFF + 1024)
#define SEL_OFF (REDI_OFF + 1024)
#define WSUM_OFF (SEL_OFF + 256)
#define LDS_TOTAL (WSUM_OFF + 16)     // 133392 < 160K (1 block/CU)

// workspace layout
#define WS_HI (8192 * 4)              // csq first (32KB)
#define CBW_HALVES (NQ * 8 * KB * 32) // 2,097,152 halves per array
#define WS_LO (WS_HI + CBW_HALVES * 2)

// Explicit drain of outstanding global_load_lds before barriers (R4: required
// for graph-replay correctness; free when counter already 0).
#define DRAIN_VMEM() asm volatile("s_waitcnt vmcnt(0)" ::: "memory")

// ---------------- init: codebook row norms (fp32) + scalar outputs ----------------
__global__ void init_cbsq_kernel(const float* __restrict__ cb, const int* __restrict__ sr,
                                 float* __restrict__ csq, float* __restrict__ out) {
    int gid = blockIdx.x * blockDim.x + threadIdx.x;
    int row = gid >> 6;
    int lane = gid & 63;
    float4 v = ((const float4*)(cb + (size_t)row * D_))[lane];
    float s = fmaf(v.x, v.x, fmaf(v.y, v.y, fmaf(v.z, v.z, v.w * v.w)));
#pragma unroll
    for (int off = 32; off; off >>= 1) s += __shfl_down(s, off);
    if (lane == 0) csq[row] = s;
    if (gid == 0) {
        out[OUT_BW] = (float)(*sr) * (80.0f / 1000.0f);
        out[OUT_LOSS] = 0.0f;
    }
}

// ---------------- init: split codebook into f16 hi + scaled-lo, [q][dc8][code][32] ----------------
__global__ void init_split_kernel(const float* __restrict__ cb, f16* __restrict__ whi,
                                  f16* __restrict__ wlo) {
    int gid = blockIdx.x * 256 + threadIdx.x;   // (q*8+dc)*1024 + k
    int qdc = gid >> 10, k = gid & 1023;
    int q = qdc >> 3, dc = qdc & 7;
    const float* src = cb + ((size_t)(q * 1024 + k)) * 256 + dc * 32;
    size_t wo = (size_t)gid * 32;
#pragma unroll
    for (int jj = 0; jj < 4; ++jj) {
        float4 a = ((const float4*)src)[jj * 2];
        float4 c = ((const float4*)src)[jj * 2 + 1];
        float vals[8] = {a.x, a.y, a.z, a.w, c.x, c.y, c.z, c.w};
        f16x8 hv, lv;
#pragma unroll
        for (int i = 0; i < 8; ++i) {
            f16 h = (f16)vals[i];
            hv[i] = h;
            lv[i] = (f16)((vals[i] - (float)h) * SCALE_UP);   // scaled lo: no f16 underflow
        }
        *(f16x8*)&whi[wo + jj * 8] = hv;
        *(f16x8*)&wlo[wo + jj * 8] = lv;
    }
}

// ---------------- async stage one 32KB super-tile (b1 16KB || b2s 16KB) ----------------
// g = q*32 + s*8 + dc : codes [s*256, +256) x dims [dc*32, +32), both kinds
__device__ __forceinline__ void stage_tile(const f16* __restrict__ whi, const f16* __restrict__ wlo,
                                           char* smem, int g, int tid) {
    const int q = g >> 5, s = (g >> 3) & 3, dc = g & 7;
    const size_t src_off = ((size_t)((q * 8 + dc) * 1024 + s * 256)) * 32;
    char* lb = smem + BBUF_OFF + (g & 1) * BTILE;
#pragma unroll
    for (int j = 0; j < 4; ++j) {
        const int v = j * 256 + tid;               // 16B-unit index in half-tile [0,1024)
        const int u = v ^ ((v >> 3) & 7);          // fetch-side swizzle (self-inverse)
        const size_t go = src_off + (size_t)u * 8;
        char* lp = lb + (j * 4096 + (tid & 192) * 16);   // wave-uniform base; lane +lane*16
        __builtin_amdgcn_global_load_lds((const __attribute__((address_space(1))) void*)(whi + go),
                                         (__attribute__((address_space(3))) void*)lp, 16, 0, 0);
        __builtin_amdgcn_global_load_lds((const __attribute__((address_space(1))) void*)(wlo + go),
                                         (__attribute__((address_space(3))) void*)(lp + 16384), 16, 0, 0);
    }
}

// ---------------- main RVQ kernel: 4-product split-f16 MFMA GEMM + fused argmin ----------------
extern "C" __global__ __launch_bounds__(NTHR, 1)
void rvq_kernel(const float* __restrict__ x, const float* __restrict__ cb,
                const float* __restrict__ csq, const f16* __restrict__ whi,
                const f16* __restrict__ wlo, float* __restrict__ out) {
    extern __shared__ char smem[];
    f16* rs = (f16*)smem;                          // [64][512] halves, granule-swizzled

    const int tid = threadIdx.x;
    const int w = tid >> 6;
    const int l = tid & 63;
    const int l15 = l & 15;
    const int q4 = l >> 4;
    const int ww = l15 * 4 + q4;
    const int swzo = (ww ^ ((ww >> 3) & 7)) * 8;   // B-frag swizzled offset, halves

    const int b = blockIdx.x >> 7;
    const int t0 = (blockIdx.x & 127) * TT;
    const float* xb = x + (size_t)b * D_ * T_;

    stage_tile(whi, wlo, smem, 0, tid);            // prefetch first super-tile

    // residual init: rs[t][d] split of x[b][d][t0+t] (coalesced over t); swizzled store
    for (int d = tid >> 6; d < D_; d += 4) {
        float v = xb[(size_t)d * T_ + t0 + l];
        f16 h = (f16)v;
        const int sw = l & 7;
        rs[l * 512 + (((d >> 3) ^ sw) << 3) + (d & 7)] = h;
        rs[l * 512 + ((((d >> 3) + 32) ^ sw) << 3) + (d & 7)] = (f16)((v - (float)h) * SCALE_UP);
    }

    float ssq = 0.0f;
    const f16 kdn = (f16)SCALE_DN;

    for (int q = 0; q < NQ; ++q) {
        const float* cbq = cb + (size_t)q * KB * D_;
        float bval[16];
        int bidx[16];
#pragma unroll
        for (int e = 0; e < 16; ++e) { bval[e] = INFINITY; bidx[e] = 0; }

        for (int s = 0; s < 4; ++s) {              // 4 sweeps of 256 codes
            f32x4 ah[4][4], am[4][4];              // 128 acc VGPRs
#pragma unroll
            for (int mt = 0; mt < 4; ++mt)
#pragma unroll
                for (int nt = 0; nt < 4; ++nt) { ah[mt][nt] = (f32x4)0.0f; am[mt][nt] = (f32x4)0.0f; }

#pragma unroll 1
            for (int dc = 0; dc < 8; ++dc) {
                const int g = q * 32 + s * 8 + dc;
                DRAIN_VMEM();                       // stage(g) writes landed
                __syncthreads();                    // all reads of buf[(g+1)&1] done
                if (g + 1 < NQ * 32) stage_tile(whi, wlo, smem, g + 1, tid);
                const f16* bb = (const f16*)(smem + BBUF_OFF + (g & 1) * BTILE);
                f16x8 bf1[4], bf2[4];
#pragma unroll
                for (int nt = 0; nt < 4; ++nt) {
                    bf1[nt] = *(const f16x8*)&bb[w * 2048 + nt * 512 + swzo];
                    bf2[nt] = *(const f16x8*)&bb[8192 + w * 2048 + nt * 512 + swzo];
                }
                const int ga = dc * 4 + q4;        // h1 granule (h2s = +32)
#pragma unroll
                for (int mt = 0; mt < 4; ++mt) {
                    const int t = mt * 16 + l15;
                    const f16* rowp = rs + t * 512;
                    const int sw = t & 7;
                    f16x8 af1 = *(const f16x8*)&rowp[(ga ^ sw) << 3];
                    f16x8 af2 = *(const f16x8*)&rowp[((ga + 32) ^ sw) << 3];
                    f16x8 afu = af2 * kdn;         // true lo (ll term)
#pragma unroll
                    for (int nt = 0; nt < 4; ++nt) {
                        ah[mt][nt] = __builtin_amdgcn_mfma_f32_16x16x32_f16(af1, bf1[nt], ah[mt][nt], 0, 0, 0);
                        am[mt][nt] = __builtin_amdgcn_mfma_f32_16x16x32_f16(af2, bf1[nt], am[mt][nt], 0, 0, 0);
                        am[mt][nt] = __builtin_amdgcn_mfma_f32_16x16x32_f16(af1, bf2[nt], am[mt][nt], 0, 0, 0);
                        am[mt][nt] = __builtin_amdgcn_mfma_f32_16x16x32_f16(afu, bf2[nt], am[mt][nt], 0, 0, 0);
                    }
                }
            }
            // fold sweep into per-lane running best (codes ascending -> strict < keeps first)
            const int cbase = s * 256 + w * 64 + l15;
#pragma unroll
            for (int nt = 0; nt < 4; ++nt) {
                const int code = cbase + nt * 16;
                const float cq = csq[q * KB + code];
#pragma unroll
                for (int mt = 0; mt < 4; ++mt)
#pragma unroll
                    for (int rg = 0; rg < 4; ++rg) {
                        const float dot = fmaf(am[mt][nt][rg], SCALE_DN, ah[mt][nt][rg]);
                        const float dist = fmaf(-2.0f, dot, cq);
                        const int e = mt * 4 + rg;
                        if (dist < bval[e]) { bval[e] = dist; bidx[e] = code; }
                    }
            }
        }
        // butterfly across the 16 lanes sharing each t (xor masks < 16 stay in group)
#pragma unroll
        for (int m = 1; m < 16; m <<= 1) {
#pragma unroll
            for (int e = 0; e < 16; ++e) {
                const float ov = __shfl_xor(bval[e], m);
                const int oi = __shfl_xor(bidx[e], m);
                if (ov < bval[e] || (ov == bval[e] && oi < bidx[e])) { bval[e] = ov; bidx[e] = oi; }
            }
        }
        float* redv = (float*)(smem + RED_OFF);
        int* redi = (int*)(smem + REDI_OFF);
        int* sel = (int*)(smem + SEL_OFF);
        if (l15 == 0) {
#pragma unroll
            for (int mt = 0; mt < 4; ++mt)
#pragma unroll
                for (int rg = 0; rg < 4; ++rg) {
                    const int t = mt * 16 + q4 * 4 + rg;   // C-layout row ownership
                    redv[w * 64 + t] = bval[mt * 4 + rg];
                    redi[w * 64 + t] = bidx[mt * 4 + rg];
                }
        }
        DRAIN_VMEM();
        __syncthreads();
        if (tid < TT) {
            float bv = redv[tid];
            int bi = redi[tid];
#pragma unroll
            for (int w2 = 1; w2 < 4; ++w2) {
                const float v = redv[w2 * 64 + tid];
                const int ii = redi[w2 * 64 + tid];
                if (v < bv || (v == bv && ii < bi)) { bv = v; bi = ii; }
            }
            sel[tid] = bi;
            out[OUT_CODES + ((size_t)q * B_ + b) * T_ + t0 + tid] = (float)bi;
        }
        DRAIN_VMEM();
        __syncthreads();
        // residual update: fp32 = h1 + h2s*2^-11, subtract cb row, re-split; ssq
        {
            const int t = tid & 63, ch = tid >> 6;  // thread: row t, 64-half chunk ch
            const float* crow = cbq + (size_t)sel[t] * D_ + ch * 64;
            f16* rowp = rs + t * 512;
            const int sw = t & 7;
#pragma unroll
            for (int jj = 0; jj < 8; ++jj) {
                const int g1 = ((ch * 8 + jj) ^ sw) << 3;
                const int g2 = ((ch * 8 + jj + 32) ^ sw) << 3;
                f16x8 hv = *(const f16x8*)&rowp[g1];
                f16x8 lv = *(const f16x8*)&rowp[g2];
                const float4 c0 = *(const float4*)&crow[jj * 8];
                const float4 c1 = *(const float4*)&crow[jj * 8 + 4];
                const float cc[8] = {c0.x, c0.y, c0.z, c0.w, c1.x, c1.y, c1.z, c1.w};
                f16x8 nh, nl;
#pragma unroll
                for (int i = 0; i < 8; ++i) {
                    const float r = fmaf((float)lv[i], SCALE_DN, (float)hv[i]);
                    const float nv = r - cc[i];
                    ssq = fmaf(nv, nv, ssq);
                    const f16 h = (f16)nv;
                    nh[i] = h;
                    nl[i] = (f16)((nv - (float)h) * SCALE_UP);
                }
                *(f16x8*)&rowp[g1] = nh;
                *(f16x8*)&rowp[g2] = nl;
            }
        }
        // next sweep's first __syncthreads orders rs writes before A-frag reads
    }
    __syncthreads();
    // quantized = x - r_final, [B][D][T], coalesced over t
    {
        float* outq = out + (size_t)b * D_ * T_;
        for (int d = tid >> 6; d < D_; d += 4) {
            const int sw = l & 7;
            const float h1 = (float)rs[l * 512 + (((d >> 3) ^ sw) << 3) + (d & 7)];
            const float h2 = (float)rs[l * 512 + ((((d >> 3) + 32) ^ sw) << 3) + (d & 7)];
            const size_t gi = (size_t)d * T_ + t0 + l;
            outq[gi] = xb[gi] - fmaf(h2, SCALE_DN, h1);
        }
    }
    // commit loss: wave reduce -> block reduce -> one atomic
#pragma unroll
    for (int off = 32; off; off >>= 1) ssq += __shfl_down(ssq, off);
    float* wsum = (float*)(smem + WSUM_OFF);
    if (l == 0) wsum[w] = ssq;
    __syncthreads();
    if (tid == 0) {
        const float scale = 0.25f / ((float)NQ * (float)B_ * (float)D_ * (float)T_);
        atomicAdd(out + OUT_LOSS, (wsum[0] + wsum[1] + wsum[2] + wsum[3]) * scale);
    }
}

extern "C" void kernel_launch(void* const* d_in, const int* in_sizes, int n_in,
                              void* d_out, int out_size, void* d_ws, size_t ws_size,
                              hipStream_t stream) {
    const float* x = (const float*)d_in[0];
    const int* sr = (const int*)d_in[1];
    const float* cb = (const float*)d_in[2];
    float* out = (float*)d_out;
    float* csq = (float*)d_ws;
    f16* whi = (f16*)((char*)d_ws + WS_HI);
    f16* wlo = (f16*)((char*)d_ws + WS_LO);

    hipFuncSetAttribute((const void*)rvq_kernel, hipFuncAttributeMaxDynamicSharedMemorySize,
                        LDS_TOTAL);

    init_cbsq_kernel<<<2048, 256, 0, stream>>>(cb, sr, csq, out);
    init_split_kernel<<<256, 256, 0, stream>>>(cb, whi, wlo);
    rvq_kernel<<<B_ * (T_ / TT), NTHR, LDS_TOTAL, stream>>>(x, cb, csq, whi, wlo, out);
}

// Round 7
// 1256.812 us; speedup vs baseline: 4.7460x; 1.2019x over previous
//
#include <hip/hip_runtime.h>
#include <math.h>

typedef _Float16 f16;
typedef f16 f16x8 __attribute__((ext_vector_type(8)));
typedef float f32x4 __attribute__((ext_vector_type(4)));

#define B_ 8
#define D_ 256
#define T_ 8192
#define NQ 8
#define KB 1024
#define TT 64
#define NTHR 256
#define SCALE_UP 2048.0f
#define SCALE_DN 4.8828125e-4f        // 2^-11

#define OUT_CODES (B_ * D_ * T_)      // 16777216
#define OUT_BW (OUT_CODES + NQ * B_ * T_)
#define OUT_LOSS (OUT_BW + 1)

// rs: 64 rows x 512 halves (h1 granules 0..31, h2s granules 32..63),
// granule (8 halves) swizzled: stored at g ^ (t & 7). No pad.
#define R_BYTES 65536
#define RED_OFF R_BYTES               // redv[256] f32
#define REDI_OFF (RED_OFF + 1024)     // redi[256] i32
#define SEL_OFF (REDI_OFF + 1024)     // sel[64]
#define WSUM_OFF (SEL_OFF + 256)
#define LDS_TOTAL (WSUM_OFF + 16)     // 67856 -> 2 blocks/CU

// workspace layout
#define WS_HI (8192 * 4)              // csq first (32KB)
#define CBW_HALVES (NQ * 8 * KB * 32) // 2,097,152 halves per array
#define WS_LO (WS_HI + CBW_HALVES * 2)

// ---------------- init: codebook row norms (fp32) + scalar outputs ----------------
__global__ void init_cbsq_kernel(const float* __restrict__ cb, const int* __restrict__ sr,
                                 float* __restrict__ csq, float* __restrict__ out) {
    int gid = blockIdx.x * blockDim.x + threadIdx.x;
    int row = gid >> 6;
    int lane = gid & 63;
    float4 v = ((const float4*)(cb + (size_t)row * D_))[lane];
    float s = fmaf(v.x, v.x, fmaf(v.y, v.y, fmaf(v.z, v.z, v.w * v.w)));
#pragma unroll
    for (int off = 32; off; off >>= 1) s += __shfl_down(s, off);
    if (lane == 0) csq[row] = s;
    if (gid == 0) {
        out[OUT_BW] = (float)(*sr) * (80.0f / 1000.0f);
        out[OUT_LOSS] = 0.0f;
    }
}

// ---------------- init: split codebook into f16 hi + scaled-lo, [q][dc8][code][32] ----------------
__global__ void init_split_kernel(const float* __restrict__ cb, f16* __restrict__ whi,
                                  f16* __restrict__ wlo) {
    int gid = blockIdx.x * 256 + threadIdx.x;   // (q*8+dc)*1024 + k
    int qdc = gid >> 10, k = gid & 1023;
    int q = qdc >> 3, dc = qdc & 7;
    const float* src = cb + ((size_t)(q * 1024 + k)) * 256 + dc * 32;
    size_t wo = (size_t)gid * 32;
#pragma unroll
    for (int jj = 0; jj < 4; ++jj) {
        float4 a = ((const float4*)src)[jj * 2];
        float4 c = ((const float4*)src)[jj * 2 + 1];
        float vals[8] = {a.x, a.y, a.z, a.w, c.x, c.y, c.z, c.w};
        f16x8 hv, lv;
#pragma unroll
        for (int i = 0; i < 8; ++i) {
            f16 h = (f16)vals[i];
            hv[i] = h;
            lv[i] = (f16)((vals[i] - (float)h) * SCALE_UP);   // scaled lo: no f16 underflow
        }
        *(f16x8*)&whi[wo + jj * 8] = hv;
        *(f16x8*)&wlo[wo + jj * 8] = lv;
    }
}

// ---------------- main RVQ kernel: 4-product split-f16 MFMA GEMM, B direct from L2 ----------------
extern "C" __global__ __launch_bounds__(NTHR, 2)
void rvq_kernel(const float* __restrict__ x, const float* __restrict__ cb,
                const float* __restrict__ csq, const f16* __restrict__ whi,
                const f16* __restrict__ wlo, float* __restrict__ out) {
    extern __shared__ char smem[];
    f16* rs = (f16*)smem;                          // [64][512] halves, granule-swizzled
    float* redv = (float*)(smem + RED_OFF);
    int* redi = (int*)(smem + REDI_OFF);
    int* sel = (int*)(smem + SEL_OFF);
    float* wsum = (float*)(smem + WSUM_OFF);

    const int tid = threadIdx.x;
    const int w = tid >> 6;
    const int l = tid & 63;
    const int l15 = l & 15;
    const int q4 = l >> 4;

    const int b = blockIdx.x >> 7;
    const int t0 = (blockIdx.x & 127) * TT;
    const float* xb = x + (size_t)b * D_ * T_;

    // residual init: rs[t][d] split of x[b][d][t0+t] (coalesced over t); swizzled store
    for (int d = tid >> 6; d < D_; d += 4) {
        float v = xb[(size_t)d * T_ + t0 + l];
        f16 h = (f16)v;
        const int sw = l & 7;
        rs[l * 512 + (((d >> 3) ^ sw) << 3) + (d & 7)] = h;
        rs[l * 512 + ((((d >> 3) + 32) ^ sw) << 3) + (d & 7)] = (f16)((v - (float)h) * SCALE_UP);
    }

    float ssq = 0.0f;
    const f16 kdn = (f16)SCALE_DN;

    for (int q = 0; q < NQ; ++q) {
        const float* cbq = cb + (size_t)q * KB * D_;
        const char* wq = (const char*)(whi + (size_t)q * 8 * KB * 32);
        const char* lq = (const char*)(wlo + (size_t)q * 8 * KB * 32);

        __syncthreads();   // rs ready (init or prev-q update); redv/redi free for this q

        for (int s = 0; s < 4; ++s) {              // 4 sweeps of 256 codes; wave stripe = 64
            // per-lane byte offsets into [code][32] tile: code*64 + q4*16
            int voff[4];
#pragma unroll
            for (int nt = 0; nt < 4; ++nt)
                voff[nt] = (s * 256 + w * 64 + nt * 16 + l15) * 64 + q4 * 16;

            f32x4 ah[4][4], am[4][4];              // 128 acc VGPRs
#pragma unroll
            for (int mt = 0; mt < 4; ++mt)
#pragma unroll
                for (int nt = 0; nt < 4; ++nt) { ah[mt][nt] = (f32x4)0.0f; am[mt][nt] = (f32x4)0.0f; }

#pragma unroll 1
            for (int dc = 0; dc < 8; ++dc) {
                // B frags direct from L2-resident split workspace (disjoint per wave)
                const char* bp1 = wq + dc * 65536;
                const char* bp2 = lq + dc * 65536;
                f16x8 bf1[4], bf2[4];
#pragma unroll
                for (int nt = 0; nt < 4; ++nt) {
                    bf1[nt] = *(const f16x8*)(bp1 + voff[nt]);
                    bf2[nt] = *(const f16x8*)(bp2 + voff[nt]);
                }
                const int ga = dc * 4 + q4;        // h1 granule (h2s = +32)
#pragma unroll
                for (int mt = 0; mt < 4; ++mt) {
                    const int t = mt * 16 + l15;
                    const f16* rowp = rs + t * 512;
                    const int sw = t & 7;
                    f16x8 af1 = *(const f16x8*)&rowp[(ga ^ sw) << 3];
                    f16x8 af2 = *(const f16x8*)&rowp[((ga + 32) ^ sw) << 3];
                    f16x8 afu = af2 * kdn;         // true lo (ll term)
#pragma unroll
                    for (int nt = 0; nt < 4; ++nt) {
                        ah[mt][nt] = __builtin_amdgcn_mfma_f32_16x16x32_f16(af1, bf1[nt], ah[mt][nt], 0, 0, 0);
                        am[mt][nt] = __builtin_amdgcn_mfma_f32_16x16x32_f16(af2, bf1[nt], am[mt][nt], 0, 0, 0);
                        am[mt][nt] = __builtin_amdgcn_mfma_f32_16x16x32_f16(af1, bf2[nt], am[mt][nt], 0, 0, 0);
                        am[mt][nt] = __builtin_amdgcn_mfma_f32_16x16x32_f16(afu, bf2[nt], am[mt][nt], 0, 0, 0);
                    }
                }
            }
            // fold sweep (codes ascending -> strict < keeps first)
            float bval[16];
            int bidx[16];
#pragma unroll
            for (int e = 0; e < 16; ++e) { bval[e] = INFINITY; bidx[e] = 0; }
            const int cbase = s * 256 + w * 64 + l15;
#pragma unroll
            for (int nt = 0; nt < 4; ++nt) {
                const int code = cbase + nt * 16;
                const float cq = csq[q * KB + code];
#pragma unroll
                for (int mt = 0; mt < 4; ++mt)
#pragma unroll
                    for (int rg = 0; rg < 4; ++rg) {
                        const float dot = fmaf(am[mt][nt][rg], SCALE_DN, ah[mt][nt][rg]);
                        const float dist = fmaf(-2.0f, dot, cq);
                        const int e = mt * 4 + rg;
                        if (dist < bval[e]) { bval[e] = dist; bidx[e] = code; }
                    }
            }
            // butterfly across the 16 lanes sharing each t
#pragma unroll
            for (int m = 1; m < 16; m <<= 1) {
#pragma unroll
                for (int e = 0; e < 16; ++e) {
                    const float ov = __shfl_xor(bval[e], m);
                    const int oi = __shfl_xor(bidx[e], m);
                    if (ov < bval[e] || (ov == bval[e] && oi < bidx[e])) { bval[e] = ov; bidx[e] = oi; }
                }
            }
            // owner lanes fold into cross-sweep running best in LDS (sweeps ascend -> strict <)
            if (l15 == 0) {
#pragma unroll
                for (int mt = 0; mt < 4; ++mt)
#pragma unroll
                    for (int rg = 0; rg < 4; ++rg) {
                        const int t = mt * 16 + q4 * 4 + rg;   // C-layout row ownership
                        const int idx = w * 64 + t;
                        const float nv = bval[mt * 4 + rg];
                        const int ni = bidx[mt * 4 + rg];
                        if (s == 0 || nv < redv[idx] || (nv == redv[idx] && ni < redi[idx])) {
                            redv[idx] = nv; redi[idx] = ni;
                        }
                    }
            }
        }
        __syncthreads();   // all waves' redv/redi final
        if (tid < TT) {
            float bv = redv[tid];
            int bi = redi[tid];
#pragma unroll
            for (int w2 = 1; w2 < 4; ++w2) {
                const float v = redv[w2 * 64 + tid];
                const int ii = redi[w2 * 64 + tid];
                if (v < bv || (v == bv && ii < bi)) { bv = v; bi = ii; }
            }
            sel[tid] = bi;
            out[OUT_CODES + ((size_t)q * B_ + b) * T_ + t0 + tid] = (float)bi;
        }
        __syncthreads();   // sel ready; all K-loop rs reads long done
        // residual update: fp32 = h1 + h2s*2^-11, subtract cb row, re-split; ssq
        {
            const int t = tid & 63, ch = tid >> 6;  // row t, 64-half chunk ch
            const float* crow = cbq + (size_t)sel[t] * D_ + ch * 64;
            f16* rowp = rs + t * 512;
            const int sw = t & 7;
#pragma unroll
            for (int jj = 0; jj < 8; ++jj) {
                const int g1 = ((ch * 8 + jj) ^ sw) << 3;
                const int g2 = ((ch * 8 + jj + 32) ^ sw) << 3;
                f16x8 hv = *(const f16x8*)&rowp[g1];
                f16x8 lv = *(const f16x8*)&rowp[g2];
                const float4 c0 = *(const float4*)&crow[jj * 8];
                const float4 c1 = *(const float4*)&crow[jj * 8 + 4];
                const float cc[8] = {c0.x, c0.y, c0.z, c0.w, c1.x, c1.y, c1.z, c1.w};
                f16x8 nh, nl;
#pragma unroll
                for (int i = 0; i < 8; ++i) {
                    const float r = fmaf((float)lv[i], SCALE_DN, (float)hv[i]);
                    const float nv = r - cc[i];
                    ssq = fmaf(nv, nv, ssq);
                    const f16 h = (f16)nv;
                    nh[i] = h;
                    nl[i] = (f16)((nv - (float)h) * SCALE_UP);
                }
                *(f16x8*)&rowp[g1] = nh;
                *(f16x8*)&rowp[g2] = nl;
            }
        }
        // next q's top __syncthreads orders rs writes before A-frag reads
    }
    __syncthreads();
    // quantized = x - r_final, [B][D][T], coalesced over t
    {
        float* outq = out + (size_t)b * D_ * T_;
        for (int d = tid >> 6; d < D_; d += 4) {
            const int sw = l & 7;
            const float h1 = (float)rs[l * 512 + (((d >> 3) ^ sw) << 3) + (d & 7)];
            const float h2 = (float)rs[l * 512 + ((((d >> 3) + 32) ^ sw) << 3) + (d & 7)];
            const size_t gi = (size_t)d * T_ + t0 + l;
            outq[gi] = xb[gi] - fmaf(h2, SCALE_DN, h1);
        }
    }
    // commit loss: wave reduce -> block reduce -> one atomic
#pragma unroll
    for (int off = 32; off; off >>= 1) ssq += __shfl_down(ssq, off);
    if (l == 0) wsum[w] = ssq;
    __syncthreads();
    if (tid == 0) {
        const float scale = 0.25f / ((float)NQ * (float)B_ * (float)D_ * (float)T_);
        atomicAdd(out + OUT_LOSS, (wsum[0] + wsum[1] + wsum[2] + wsum[3]) * scale);
    }
}

extern "C" void kernel_launch(void* const* d_in, const int* in_sizes, int n_in,
                              void* d_out, int out_size, void* d_ws, size_t ws_size,
                              hipStream_t stream) {
    const float* x = (const float*)d_in[0];
    const int* sr = (const int*)d_in[1];
    const float* cb = (const float*)d_in[2];
    float* out = (float*)d_out;
    float* csq = (float*)d_ws;
    f16* whi = (f16*)((char*)d_ws + WS_HI);
    f16* wlo = (f16*)((char*)d_ws + WS_LO);

    hipFuncSetAttribute((const void*)rvq_kernel, hipFuncAttributeMaxDynamicSharedMemorySize,
                        LDS_TOTAL);

    init_cbsq_kernel<<<2048, 256, 0, stream>>>(cb, sr, csq, out);
    init_split_kernel<<<256, 256, 0, stream>>>(cb, whi, wlo);
    rvq_kernel<<<B_ * (T_ / TT), NTHR, LDS_TOTAL, stream>>>(x, cb, csq, whi, wlo, out);
}

// Round 8
// 1156.067 us; speedup vs baseline: 5.1596x; 1.0871x over previous
//
#include <hip/hip_runtime.h>
#include <math.h>

typedef _Float16 f16;
typedef f16 f16x8 __attribute__((ext_vector_type(8)));
typedef float f32x4 __attribute__((ext_vector_type(4)));

#define B_ 8
#define D_ 256
#define T_ 8192
#define NQ 8
#define KB 1024
#define TT 64
#define NTHR 256
#define SCALE_UP 2048.0f
#define SCALE_DN 4.8828125e-4f        // 2^-11

#define OUT_CODES (B_ * D_ * T_)      // 16777216
#define OUT_BW (OUT_CODES + NQ * B_ * T_)
#define OUT_LOSS (OUT_BW + 1)

// rs: 64 rows x 512 halves (h1 granules 0..31, h2s granules 32..63),
// granule (8 halves) swizzled: stored at g ^ (t & 7). No pad.
#define R_BYTES 65536
#define RED_OFF R_BYTES               // redv[256] f32
#define REDI_OFF (RED_OFF + 1024)     // redi[256] i32
#define SEL_OFF (REDI_OFF + 1024)     // sel[64]
#define WSUM_OFF (SEL_OFF + 256)
#define LDS_TOTAL (WSUM_OFF + 16)     // 67856 -> 2 blocks/CU

// workspace layout
#define WS_HI (8192 * 4)              // csq first (32KB)
#define CBW_HALVES (NQ * 8 * KB * 32) // 2,097,152 halves per array
#define WS_LO (WS_HI + CBW_HALVES * 2)

// ---------------- init: codebook row norms (fp32) + scalar outputs ----------------
__global__ void init_cbsq_kernel(const float* __restrict__ cb, const int* __restrict__ sr,
                                 float* __restrict__ csq, float* __restrict__ out) {
    int gid = blockIdx.x * blockDim.x + threadIdx.x;
    int row = gid >> 6;
    int lane = gid & 63;
    float4 v = ((const float4*)(cb + (size_t)row * D_))[lane];
    float s = fmaf(v.x, v.x, fmaf(v.y, v.y, fmaf(v.z, v.z, v.w * v.w)));
#pragma unroll
    for (int off = 32; off; off >>= 1) s += __shfl_down(s, off);
    if (lane == 0) csq[row] = s;
    if (gid == 0) {
        out[OUT_BW] = (float)(*sr) * (80.0f / 1000.0f);
        out[OUT_LOSS] = 0.0f;
    }
}

// ---------------- init: split codebook into f16 hi + scaled-lo, [q][dc8][code][32] ----------------
__global__ void init_split_kernel(const float* __restrict__ cb, f16* __restrict__ whi,
                                  f16* __restrict__ wlo) {
    int gid = blockIdx.x * 256 + threadIdx.x;   // (q*8+dc)*1024 + k
    int qdc = gid >> 10, k = gid & 1023;
    int q = qdc >> 3, dc = qdc & 7;
    const float* src = cb + ((size_t)(q * 1024 + k)) * 256 + dc * 32;
    size_t wo = (size_t)gid * 32;
#pragma unroll
    for (int jj = 0; jj < 4; ++jj) {
        float4 a = ((const float4*)src)[jj * 2];
        float4 c = ((const float4*)src)[jj * 2 + 1];
        float vals[8] = {a.x, a.y, a.z, a.w, c.x, c.y, c.z, c.w};
        f16x8 hv, lv;
#pragma unroll
        for (int i = 0; i < 8; ++i) {
            f16 h = (f16)vals[i];
            hv[i] = h;
            lv[i] = (f16)((vals[i] - (float)h) * SCALE_UP);   // scaled lo: no f16 underflow
        }
        *(f16x8*)&whi[wo + jj * 8] = hv;
        *(f16x8*)&wlo[wo + jj * 8] = lv;
    }
}

// ---------------- main RVQ kernel: 4-product split-f16 MFMA GEMM, B direct from L2 ----------------
extern "C" __global__ __launch_bounds__(NTHR, 2)
void rvq_kernel(const float* __restrict__ x, const float* __restrict__ cb,
                const float* __restrict__ csq, const f16* __restrict__ whi,
                const f16* __restrict__ wlo, float* __restrict__ out) {
    extern __shared__ char smem[];
    f16* rs = (f16*)smem;                          // [64][512] halves, granule-swizzled
    float* redv = (float*)(smem + RED_OFF);
    int* redi = (int*)(smem + REDI_OFF);
    int* sel = (int*)(smem + SEL_OFF);
    float* wsum = (float*)(smem + WSUM_OFF);

    const int tid = threadIdx.x;
    const int w = tid >> 6;
    const int l = tid & 63;
    const int l15 = l & 15;
    const int q4 = l >> 4;

    const int b = blockIdx.x >> 7;
    const int t0 = (blockIdx.x & 127) * TT;
    const float* xb = x + (size_t)b * D_ * T_;

    // residual init: rs[t][d] split of x[b][d][t0+t] (coalesced over t); swizzled store
    for (int d = tid >> 6; d < D_; d += 4) {
        float v = xb[(size_t)d * T_ + t0 + l];
        f16 h = (f16)v;
        const int sw = l & 7;
        rs[l * 512 + (((d >> 3) ^ sw) << 3) + (d & 7)] = h;
        rs[l * 512 + ((((d >> 3) + 32) ^ sw) << 3) + (d & 7)] = (f16)((v - (float)h) * SCALE_UP);
    }

    float ssq = 0.0f;
    const f16 kdn = (f16)SCALE_DN;

    for (int q = 0; q < NQ; ++q) {
        const float* cbq = cb + (size_t)q * KB * D_;
        const char* wq = (const char*)(whi + (size_t)q * 8 * KB * 32);
        const char* lq = (const char*)(wlo + (size_t)q * 8 * KB * 32);

        __syncthreads();   // rs ready (init or prev-q update); redv/redi free for this q

        // cross-sweep running best, per-lane registers (slot = (mt,rg) row ownership,
        // sweep-invariant; codes ascend across sweeps -> strict < keeps first min)
        float bval[16];
        int bidx[16];
#pragma unroll
        for (int e = 0; e < 16; ++e) { bval[e] = INFINITY; bidx[e] = 0; }

        for (int s = 0; s < 4; ++s) {              // 4 sweeps of 256 codes; wave stripe = 64
            // per-lane byte offsets into [code][32] tile: code*64 + q4*16
            int voff[4];
#pragma unroll
            for (int nt = 0; nt < 4; ++nt)
                voff[nt] = (s * 256 + w * 64 + nt * 16 + l15) * 64 + q4 * 16;

            f32x4 ah[4][4], am[4][4];              // 128 acc VGPRs
#pragma unroll
            for (int mt = 0; mt < 4; ++mt)
#pragma unroll
                for (int nt = 0; nt < 4; ++nt) { ah[mt][nt] = (f32x4)0.0f; am[mt][nt] = (f32x4)0.0f; }

            // B-frag software pipeline: cur in registers, next prefetched during MFMA
            f16x8 cb1[4], cb2[4];
#pragma unroll
            for (int nt = 0; nt < 4; ++nt) {
                cb1[nt] = *(const f16x8*)(wq + voff[nt]);
                cb2[nt] = *(const f16x8*)(lq + voff[nt]);
            }

#pragma unroll 1
            for (int dc = 0; dc < 8; ++dc) {
                f16x8 nb1[4], nb2[4];
                if (dc < 7) {
                    const char* bp1 = wq + (dc + 1) * 65536;
                    const char* bp2 = lq + (dc + 1) * 65536;
#pragma unroll
                    for (int nt = 0; nt < 4; ++nt) {
                        nb1[nt] = *(const f16x8*)(bp1 + voff[nt]);
                        nb2[nt] = *(const f16x8*)(bp2 + voff[nt]);
                    }
                }
                const int ga = dc * 4 + q4;        // h1 granule (h2s = +32)
#pragma unroll
                for (int mt = 0; mt < 4; ++mt) {
                    const int t = mt * 16 + l15;
                    const f16* rowp = rs + t * 512;
                    const int sw = t & 7;
                    f16x8 af1 = *(const f16x8*)&rowp[(ga ^ sw) << 3];
                    f16x8 af2 = *(const f16x8*)&rowp[((ga + 32) ^ sw) << 3];
                    f16x8 afu = af2 * kdn;         // true lo (ll term)
#pragma unroll
                    for (int nt = 0; nt < 4; ++nt) {
                        ah[mt][nt] = __builtin_amdgcn_mfma_f32_16x16x32_f16(af1, cb1[nt], ah[mt][nt], 0, 0, 0);
                        am[mt][nt] = __builtin_amdgcn_mfma_f32_16x16x32_f16(af2, cb1[nt], am[mt][nt], 0, 0, 0);
                        am[mt][nt] = __builtin_amdgcn_mfma_f32_16x16x32_f16(af1, cb2[nt], am[mt][nt], 0, 0, 0);
                        am[mt][nt] = __builtin_amdgcn_mfma_f32_16x16x32_f16(afu, cb2[nt], am[mt][nt], 0, 0, 0);
                    }
                }
                if (dc < 7) {
#pragma unroll
                    for (int nt = 0; nt < 4; ++nt) { cb1[nt] = nb1[nt]; cb2[nt] = nb2[nt]; }
                }
            }
            // fold sweep into cross-sweep per-lane best (codes ascending -> strict <)
            const int cbase = s * 256 + w * 64 + l15;
#pragma unroll
            for (int nt = 0; nt < 4; ++nt) {
                const int code = cbase + nt * 16;
                const float cq = csq[q * KB + code];
#pragma unroll
                for (int mt = 0; mt < 4; ++mt)
#pragma unroll
                    for (int rg = 0; rg < 4; ++rg) {
                        const float dot = fmaf(am[mt][nt][rg], SCALE_DN, ah[mt][nt][rg]);
                        const float dist = fmaf(-2.0f, dot, cq);
                        const int e = mt * 4 + rg;
                        if (dist < bval[e]) { bval[e] = dist; bidx[e] = code; }
                    }
            }
        }
        // once per q: butterfly across the 16 lanes sharing each t
#pragma unroll
        for (int m = 1; m < 16; m <<= 1) {
#pragma unroll
            for (int e = 0; e < 16; ++e) {
                const float ov = __shfl_xor(bval[e], m);
                const int oi = __shfl_xor(bidx[e], m);
                if (ov < bval[e] || (ov == bval[e] && oi < bidx[e])) { bval[e] = ov; bidx[e] = oi; }
            }
        }
        if (l15 == 0) {
#pragma unroll
            for (int mt = 0; mt < 4; ++mt)
#pragma unroll
                for (int rg = 0; rg < 4; ++rg) {
                    const int t = mt * 16 + q4 * 4 + rg;   // C-layout row ownership
                    redv[w * 64 + t] = bval[mt * 4 + rg];
                    redi[w * 64 + t] = bidx[mt * 4 + rg];
                }
        }
        __syncthreads();   // all waves' redv/redi final
        if (tid < TT) {
            float bv = redv[tid];
            int bi = redi[tid];
#pragma unroll
            for (int w2 = 1; w2 < 4; ++w2) {
                const float v = redv[w2 * 64 + tid];
                const int ii = redi[w2 * 64 + tid];
                if (v < bv || (v == bv && ii < bi)) { bv = v; bi = ii; }
            }
            sel[tid] = bi;
            out[OUT_CODES + ((size_t)q * B_ + b) * T_ + t0 + tid] = (float)bi;
        }
        __syncthreads();   // sel ready; all K-loop rs reads long done
        // residual update: fp32 = h1 + h2s*2^-11, subtract cb row, re-split; ssq
        {
            const int t = tid & 63, ch = tid >> 6;  // row t, 64-half chunk ch
            const float* crow = cbq + (size_t)sel[t] * D_ + ch * 64;
            f16* rowp = rs + t * 512;
            const int sw = t & 7;
#pragma unroll
            for (int jj = 0; jj < 8; ++jj) {
                const int g1 = ((ch * 8 + jj) ^ sw) << 3;
                const int g2 = ((ch * 8 + jj + 32) ^ sw) << 3;
                f16x8 hv = *(const f16x8*)&rowp[g1];
                f16x8 lv = *(const f16x8*)&rowp[g2];
                const float4 c0 = *(const float4*)&crow[jj * 8];
                const float4 c1 = *(const float4*)&crow[jj * 8 + 4];
                const float cc[8] = {c0.x, c0.y, c0.z, c0.w, c1.x, c1.y, c1.z, c1.w};
                f16x8 nh, nl;
#pragma unroll
                for (int i = 0; i < 8; ++i) {
                    const float r = fmaf((float)lv[i], SCALE_DN, (float)hv[i]);
                    const float nv = r - cc[i];
                    ssq = fmaf(nv, nv, ssq);
                    const f16 h = (f16)nv;
                    nh[i] = h;
                    nl[i] = (f16)((nv - (float)h) * SCALE_UP);
                }
                *(f16x8*)&rowp[g1] = nh;
                *(f16x8*)&rowp[g2] = nl;
            }
        }
        // next q's top __syncthreads orders rs writes before A-frag reads
    }
    __syncthreads();
    // quantized = x - r_final, [B][D][T], coalesced over t
    {
        float* outq = out + (size_t)b * D_ * T_;
        for (int d = tid >> 6; d < D_; d += 4) {
            const int sw = l & 7;
            const float h1 = (float)rs[l * 512 + (((d >> 3) ^ sw) << 3) + (d & 7)];
            const float h2 = (float)rs[l * 512 + ((((d >> 3) + 32) ^ sw) << 3) + (d & 7)];
            const size_t gi = (size_t)d * T_ + t0 + l;
            outq[gi] = xb[gi] - fmaf(h2, SCALE_DN, h1);
        }
    }
    // commit loss: wave reduce -> block reduce -> one atomic
#pragma unroll
    for (int off = 32; off; off >>= 1) ssq += __shfl_down(ssq, off);
    if (l == 0) wsum[w] = ssq;
    __syncthreads();
    if (tid == 0) {
        const float scale = 0.25f / ((float)NQ * (float)B_ * (float)D_ * (float)T_);
        atomicAdd(out + OUT_LOSS, (wsum[0] + wsum[1] + wsum[2] + wsum[3]) * scale);
    }
}

extern "C" void kernel_launch(void* const* d_in, const int* in_sizes, int n_in,
                              void* d_out, int out_size, void* d_ws, size_t ws_size,
                              hipStream_t stream) {
    const float* x = (const float*)d_in[0];
    const int* sr = (const int*)d_in[1];
    const float* cb = (const float*)d_in[2];
    float* out = (float*)d_out;
    float* csq = (float*)d_ws;
    f16* whi = (f16*)((char*)d_ws + WS_HI);
    f16* wlo = (f16*)((char*)d_ws + WS_LO);

    hipFuncSetAttribute((const void*)rvq_kernel, hipFuncAttributeMaxDynamicSharedMemorySize,
                        LDS_TOTAL);

    init_cbsq_kernel<<<2048, 256, 0, stream>>>(cb, sr, csq, out);
    init_split_kernel<<<256, 256, 0, stream>>>(cb, whi, wlo);
    rvq_kernel<<<B_ * (T_ / TT), NTHR, LDS_TOTAL, stream>>>(x, cb, csq, whi, wlo, out);
}